// Round 16
// baseline (518.697 us; speedup 1.0000x reference)
//
#include <hip/hip_runtime.h>

// NonLocalLayer  B=8, C=128, MID=64, OUT=128, T=4, N=512, TN=2048
// All-fp32 (reference dtype). Pure GPU pipeline, identical work every call
// (no capture branching, no host compute — r15 tripwire fix).
//
// Math (validated on-device r15 via host-compute twin, absmax 7.8e-3):
//   proj  : theta/phi/g [64][2048] = relu(W[64][128] @ pc[128][2048] + b)
//   s[q,k] = sum_m theta[m,q] * phi[m,k]
//   softmax over q (axis=1): w[q,k] = exp(s[q,k]-M_k) / Z_k
//   y[m,q] = sum_k w[q,k] * g[m,k]
//   refined[o,q] = relu(RW[o][m] @ y + rb[o])
//   out[b,c,t,n] = refined[t*32+(n>>4)][(n&15)*128+c] + pc[b,c,t,n]
//
// ws: nb=8 single pass needs 16,908,288 B; nb=1 (8 passes) 2,113,536 B.

constexpr int NL75_TN  = 2048;
constexpr int NL75_MID = 64;
constexpr int NL75_C   = 128;

__global__ void NonLocalLayer_75771813036638_kernel() {}

// ---------------- projections: proj[pj][bl][m][q] ----------------
// grid (32, 3, nb), block 256.
__global__ void nl75_proj(const float* pc, const float* w0, const float* b0,
                          const float* w1, const float* b1, const float* w2,
                          const float* b2, float* projB, int bOff, int nb) {
  __shared__ float wT[NL75_C][68];  // [c][m]
  const int qt = blockIdx.x, pj = blockIdx.y, bl = blockIdx.z;
  const int b = bOff + bl;
  const float* wp = (pj == 0) ? w0 : (pj == 1) ? w1 : w2;
  const float* bp = (pj == 0) ? b0 : (pj == 1) ? b1 : b2;
  const int tid = threadIdx.x;
  for (int i = tid; i < NL75_MID * NL75_C; i += 256)
    wT[i & 127][i >> 7] = wp[i];  // W row-major [64][128]
  __syncthreads();
  const int lq = tid & 63, mg = tid >> 6;
  const int q = qt * 64 + lq, m0 = mg * 16;
  const float* pcb = pc + (long long)b * NL75_C * NL75_TN + q;
  float acc[16];
#pragma unroll
  for (int i = 0; i < 16; i++) acc[i] = bp[m0 + i];
  for (int c = 0; c < NL75_C; c++) {
    float p = pcb[(long long)c * NL75_TN];
#pragma unroll
    for (int i = 0; i < 16; i++) acc[i] = fmaf(wT[c][m0 + i], p, acc[i]);
  }
  float* op = projB + ((long long)(pj * nb + bl) * NL75_MID) * NL75_TN + q;
#pragma unroll
  for (int i = 0; i < 16; i++)
    op[(long long)(m0 + i) * NL75_TN] = fmaxf(acc[i], 0.0f);
}

// ------------- softmax stats over q, per column k -------------
// grid (32, nb), block 256.
__global__ void nl75_stats(const float* projB, float* mOut, float* izOut,
                           int nb) {
  __shared__ float thS[NL75_MID][68];
  __shared__ float phS[NL75_MID][68];
  __shared__ float redM[16][64];
  __shared__ float redS[16][64];
  const int kt = blockIdx.x, bl = blockIdx.y;
  const int tid = threadIdx.x;
  const float* thB = projB + ((long long)(0 * nb + bl) * NL75_MID) * NL75_TN;
  const float* phB = projB + ((long long)(1 * nb + bl) * NL75_MID) * NL75_TN;
  const int k0 = kt * 64;
  for (int i = tid; i < NL75_MID * 64; i += 256) {
    int m = i >> 6, k = i & 63;
    phS[m][k] = phB[(long long)m * NL75_TN + k0 + k];
  }
  const int kx = tid & 15, qx = tid >> 4;
  float mv[4], sv[4];
#pragma unroll
  for (int j = 0; j < 4; j++) { mv[j] = -1e30f; sv[j] = 0.0f; }
  for (int qt = 0; qt < 32; qt++) {
    __syncthreads();
    for (int i = tid; i < NL75_MID * 64; i += 256) {
      int m = i >> 6, qq = i & 63;
      thS[m][qq] = thB[(long long)m * NL75_TN + qt * 64 + qq];
    }
    __syncthreads();
    float s[4][4];
#pragma unroll
    for (int i = 0; i < 4; i++)
#pragma unroll
      for (int j = 0; j < 4; j++) s[i][j] = 0.0f;
    for (int m = 0; m < NL75_MID; m++) {
      float av[4], bv[4];
#pragma unroll
      for (int i = 0; i < 4; i++) av[i] = thS[m][qx * 4 + i];
#pragma unroll
      for (int j = 0; j < 4; j++) bv[j] = phS[m][kx * 4 + j];
#pragma unroll
      for (int i = 0; i < 4; i++)
#pragma unroll
        for (int j = 0; j < 4; j++) s[i][j] = fmaf(av[i], bv[j], s[i][j]);
    }
#pragma unroll
    for (int j = 0; j < 4; j++) {
      float mx = fmaxf(fmaxf(s[0][j], s[1][j]), fmaxf(s[2][j], s[3][j]));
      float mn = fmaxf(mv[j], mx);
      float sum = __expf(s[0][j] - mn) + __expf(s[1][j] - mn) +
                  __expf(s[2][j] - mn) + __expf(s[3][j] - mn);
      sv[j] = sv[j] * __expf(mv[j] - mn) + sum;
      mv[j] = mn;
    }
  }
#pragma unroll
  for (int j = 0; j < 4; j++) {
    redM[qx][kx * 4 + j] = mv[j];
    redS[qx][kx * 4 + j] = sv[j];
  }
  __syncthreads();
  if (tid < 64) {
    float mf = -1e30f;
#pragma unroll
    for (int i = 0; i < 16; i++) mf = fmaxf(mf, redM[i][tid]);
    float sf = 0.0f;
#pragma unroll
    for (int i = 0; i < 16; i++) sf += redS[i][tid] * __expf(redM[i][tid] - mf);
    mOut[(long long)bl * NL75_TN + k0 + tid] = mf;
    izOut[(long long)bl * NL75_TN + k0 + tid] = 1.0f / sf;
  }
}

// ------------- attention apply + PV: y[m][q] -------------
// grid (32, nb), block 256.
__global__ void nl75_attn(const float* projB, const float* mIn,
                          const float* izIn, float* yOut, int nb) {
  __shared__ float thS[NL75_MID][68];
  __shared__ float phwS[NL75_MID][68];  // phase1: phi [m][k]; phase2: w [k][q]
  __shared__ float gS[NL75_MID][68];    // [k][m]
  __shared__ float mT[64], izT[64];
  const int qt = blockIdx.x, bl = blockIdx.y;
  const int tid = threadIdx.x;
  const float* thB = projB + ((long long)(0 * nb + bl) * NL75_MID) * NL75_TN;
  const float* phB = projB + ((long long)(1 * nb + bl) * NL75_MID) * NL75_TN;
  const float* gB  = projB + ((long long)(2 * nb + bl) * NL75_MID) * NL75_TN;
  const int q0 = qt * 64;
  for (int i = tid; i < NL75_MID * 64; i += 256) {
    int m = i >> 6, qq = i & 63;
    thS[m][qq] = thB[(long long)m * NL75_TN + q0 + qq];
  }
  const int kx = tid & 15, qx = tid >> 4;
  float acc[4][4];  // y[m = kx*4+i][q = q0 + qx*4+j]
#pragma unroll
  for (int i = 0; i < 4; i++)
#pragma unroll
    for (int j = 0; j < 4; j++) acc[i][j] = 0.0f;
  for (int kt = 0; kt < 32; kt++) {
    __syncthreads();
    const int k0 = kt * 64;
    for (int i = tid; i < NL75_MID * 64; i += 256) {
      int m = i >> 6, k = i & 63;
      phwS[m][k] = phB[(long long)m * NL75_TN + k0 + k];
      gS[k][m]   = gB[(long long)m * NL75_TN + k0 + k];
    }
    if (tid < 64) {
      mT[tid]  = mIn[(long long)bl * NL75_TN + k0 + tid];
      izT[tid] = izIn[(long long)bl * NL75_TN + k0 + tid];
    }
    __syncthreads();
    float s[4][4];  // s[q-sub i][k-sub j]
#pragma unroll
    for (int i = 0; i < 4; i++)
#pragma unroll
      for (int j = 0; j < 4; j++) s[i][j] = 0.0f;
    for (int m = 0; m < NL75_MID; m++) {
      float av[4], bv[4];
#pragma unroll
      for (int i = 0; i < 4; i++) av[i] = thS[m][qx * 4 + i];
#pragma unroll
      for (int j = 0; j < 4; j++) bv[j] = phwS[m][kx * 4 + j];
#pragma unroll
      for (int i = 0; i < 4; i++)
#pragma unroll
        for (int j = 0; j < 4; j++) s[i][j] = fmaf(av[i], bv[j], s[i][j]);
    }
    __syncthreads();  // all reads of phi done before overwrite with w
#pragma unroll
    for (int j = 0; j < 4; j++) {
      int k = kx * 4 + j;
      float mk = mT[k], iz = izT[k];
#pragma unroll
      for (int i = 0; i < 4; i++)
        phwS[k][qx * 4 + i] = __expf(s[i][j] - mk) * iz;  // w[k][q-local]
    }
    __syncthreads();
    for (int k = 0; k < 64; k++) {
      float gv[4], wv[4];
#pragma unroll
      for (int i = 0; i < 4; i++) gv[i] = gS[k][kx * 4 + i];
#pragma unroll
      for (int j = 0; j < 4; j++) wv[j] = phwS[k][qx * 4 + j];
#pragma unroll
      for (int i = 0; i < 4; i++)
#pragma unroll
        for (int j = 0; j < 4; j++) acc[i][j] = fmaf(gv[i], wv[j], acc[i][j]);
    }
  }
  float* yB = yOut + (long long)bl * NL75_MID * NL75_TN;
#pragma unroll
  for (int i = 0; i < 4; i++)
#pragma unroll
    for (int j = 0; j < 4; j++)
      yB[(long long)(kx * 4 + i) * NL75_TN + q0 + qx * 4 + j] = acc[i][j];
}

// ------- fused refine GEMM + scatter + residual -------
// grid (16, 4, nb) = (cg: c-block of 8, t, bl), block 256.
__global__ void nl75_refsc(const float* yIn, const float* rW, const float* rB,
                           const float* pc, float* outP, int bOff) {
  __shared__ float rwS[32][66];        // [oh][m]
  __shared__ float yS[NL75_MID][132];  // [m][qi], qi = i16*8 + cl (cl<8)
  const int cg = blockIdx.x, t = blockIdx.y, bl = blockIdx.z;
  const int b = bOff + bl, c0 = cg * 8, tid = threadIdx.x;
  for (int i = tid; i < 32 * NL75_MID; i += 256) {
    int oh = i >> 6, m = i & 63;
    rwS[oh][m] = rW[(long long)(t * 32 + oh) * NL75_MID + m];
  }
  const float* yB = yIn + (long long)bl * NL75_MID * NL75_TN;
  for (int i = tid; i < NL75_MID * 128; i += 256) {
    int m = i >> 7, qi = i & 127;
    int i16 = qi >> 3, cl = qi & 7;
    yS[m][qi] = yB[(long long)m * NL75_TN + i16 * 128 + c0 + cl];
  }
  __syncthreads();
  const int oh0 = (tid >> 5) * 4;  // 8 groups x 4 oh rows
  const int q4 = (tid & 31) * 4;   // 32 groups x 4 qi cols
  float acc[4][4];
#pragma unroll
  for (int i = 0; i < 4; i++) {
    float bias = rB[t * 32 + oh0 + i];
#pragma unroll
    for (int j = 0; j < 4; j++) acc[i][j] = bias;
  }
  for (int m = 0; m < NL75_MID; m++) {
    float yv[4];
#pragma unroll
    for (int j = 0; j < 4; j++) yv[j] = yS[m][q4 + j];
#pragma unroll
    for (int i = 0; i < 4; i++) {
      float w = rwS[oh0 + i][m];
#pragma unroll
      for (int j = 0; j < 4; j++) acc[i][j] = fmaf(w, yv[j], acc[i][j]);
    }
  }
#pragma unroll
  for (int i = 0; i < 4; i++) {
    int oh = oh0 + i;
#pragma unroll
    for (int j = 0; j < 4; j++) {
      int qi = q4 + j;
      int i16 = qi >> 3, cl = qi & 7;
      int n = oh * 16 + i16;
      long long idx = (((long long)b * 128 + c0 + cl) * 4 + t) * 512 + n;
      outP[idx] = fmaxf(acc[i][j], 0.0f) + pc[idx];
    }
  }
}

extern "C" void kernel_launch(void* const* d_in, const int* in_sizes, int n_in,
                              void* d_out, int out_size, void* d_ws, size_t ws_size,
                              hipStream_t stream) {
  const float* pc = (const float*)d_in[0];
  const float* tw = (const float*)d_in[1];
  const float* tb = (const float*)d_in[2];
  const float* pw = (const float*)d_in[3];
  const float* pb = (const float*)d_in[4];
  const float* gw = (const float*)d_in[5];
  const float* gb = (const float*)d_in[6];
  const float* rw = (const float*)d_in[7];
  const float* rb = (const float*)d_in[8];
  float* out = (float*)d_out;

  const size_t projElems = 3ull * NL75_MID * NL75_TN;           // fp32/batch
  const size_t perBatch = (projElems + 2ull * NL75_TN +
                           (size_t)NL75_MID * NL75_TN) * 4;     // 2,113,536 B
  const int nb = (ws_size >= perBatch * 8) ? 8 : 1;
  const int nloop = (nb == 8) ? 1 : 8;

  float* projB = (float*)d_ws;
  float* mW = projB + projElems * nb;
  float* izW = mW + (size_t)nb * NL75_TN;
  float* yW = izW + (size_t)nb * NL75_TN;

  for (int l = 0; l < nloop; l++) {
    const int bOff = l * nb;
    nl75_proj<<<dim3(32, 3, nb), 256, 0, stream>>>(pc, tw, tb, pw, pb, gw, gb,
                                                   projB, bOff, nb);
    nl75_stats<<<dim3(32, nb), 256, 0, stream>>>(projB, mW, izW, nb);
    nl75_attn<<<dim3(32, nb), 256, 0, stream>>>(projB, mW, izW, yW, nb);
    nl75_refsc<<<dim3(16, 4, nb), 256, 0, stream>>>(yW, rw, rb, pc, out, bOff);
  }
}

// Round 17
// 382.902 us; speedup vs baseline: 1.3546x; 1.3546x over previous
//
#include <hip/hip_runtime.h>

// NonLocalLayer  B=8, C=128, MID=64, OUT=128, T=4, N=512, TN=2048
// All-fp32. R17: occupancy fix — split stats over q (4x) and attn over k (4x)
// with exact partial-reduction, raising the hot kernels from 256 -> 1024
// blocks (1 -> 3 blocks/CU). Partials combined in nl75_sred / refsc staging.
// ws tiers: full split 30.0 MB | mid (r16-identical) 16.9 MB | low 2.1 MB.

constexpr int NL75_TN  = 2048;
constexpr int NL75_MID = 64;
constexpr int NL75_C   = 128;

__global__ void NonLocalLayer_75771813036638_kernel() {}

// ---------------- projections: proj[pj][bl][m][q] ----------------
// grid (32, 3, nb), block 256.
__global__ void nl75_proj(const float* pc, const float* w0, const float* b0,
                          const float* w1, const float* b1, const float* w2,
                          const float* b2, float* projB, int bOff, int nb) {
  __shared__ float wT[NL75_C][68];  // [c][m]
  const int qt = blockIdx.x, pj = blockIdx.y, bl = blockIdx.z;
  const int b = bOff + bl;
  const float* wp = (pj == 0) ? w0 : (pj == 1) ? w1 : w2;
  const float* bp = (pj == 0) ? b0 : (pj == 1) ? b1 : b2;
  const int tid = threadIdx.x;
  for (int i = tid; i < NL75_MID * NL75_C; i += 256)
    wT[i & 127][i >> 7] = wp[i];  // W row-major [64][128]
  __syncthreads();
  const int lq = tid & 63, mg = tid >> 6;
  const int q = qt * 64 + lq, m0 = mg * 16;
  const float* pcb = pc + (long long)b * NL75_C * NL75_TN + q;
  float acc[16];
#pragma unroll
  for (int i = 0; i < 16; i++) acc[i] = bp[m0 + i];
  for (int c = 0; c < NL75_C; c++) {
    float p = pcb[(long long)c * NL75_TN];
#pragma unroll
    for (int i = 0; i < 16; i++) acc[i] = fmaf(wT[c][m0 + i], p, acc[i]);
  }
  float* op = projB + ((long long)(pj * nb + bl) * NL75_MID) * NL75_TN + q;
#pragma unroll
  for (int i = 0; i < 16; i++)
    op[(long long)(m0 + i) * NL75_TN] = fmaxf(acc[i], 0.0f);
}

// ------------- partial softmax stats over a q-range, per column k -----------
// grid (32*qsplit, nb), block 256. blockIdx.x = kt + 32*qs.
__global__ void nl75_stats(const float* projB, float* Mp, float* Sp, int nb,
                           int qsplit) {
  __shared__ float thS[NL75_MID][68];
  __shared__ float phS[NL75_MID][68];
  __shared__ float redM[16][64];
  __shared__ float redS[16][64];
  const int kt = blockIdx.x & 31, qs = blockIdx.x >> 5, bl = blockIdx.y;
  const int tid = threadIdx.x;
  const float* thB = projB + ((long long)(0 * nb + bl) * NL75_MID) * NL75_TN;
  const float* phB = projB + ((long long)(1 * nb + bl) * NL75_MID) * NL75_TN;
  const int k0 = kt * 64;
  for (int i = tid; i < NL75_MID * 64; i += 256) {
    int m = i >> 6, k = i & 63;
    phS[m][k] = phB[(long long)m * NL75_TN + k0 + k];
  }
  const int kx = tid & 15, qx = tid >> 4;
  float mv[4], sv[4];
#pragma unroll
  for (int j = 0; j < 4; j++) { mv[j] = -1e30f; sv[j] = 0.0f; }
  const int qtN = 32 / qsplit;
  const int qtBeg = qs * qtN, qtEnd = qtBeg + qtN;
  for (int qt = qtBeg; qt < qtEnd; qt++) {
    __syncthreads();
    for (int i = tid; i < NL75_MID * 64; i += 256) {
      int m = i >> 6, qq = i & 63;
      thS[m][qq] = thB[(long long)m * NL75_TN + qt * 64 + qq];
    }
    __syncthreads();
    float s[4][4];
#pragma unroll
    for (int i = 0; i < 4; i++)
#pragma unroll
      for (int j = 0; j < 4; j++) s[i][j] = 0.0f;
    for (int m = 0; m < NL75_MID; m++) {
      float av[4], bv[4];
#pragma unroll
      for (int i = 0; i < 4; i++) av[i] = thS[m][qx * 4 + i];
#pragma unroll
      for (int j = 0; j < 4; j++) bv[j] = phS[m][kx * 4 + j];
#pragma unroll
      for (int i = 0; i < 4; i++)
#pragma unroll
        for (int j = 0; j < 4; j++) s[i][j] = fmaf(av[i], bv[j], s[i][j]);
    }
#pragma unroll
    for (int j = 0; j < 4; j++) {
      float mx = fmaxf(fmaxf(s[0][j], s[1][j]), fmaxf(s[2][j], s[3][j]));
      float mn = fmaxf(mv[j], mx);
      float sum = __expf(s[0][j] - mn) + __expf(s[1][j] - mn) +
                  __expf(s[2][j] - mn) + __expf(s[3][j] - mn);
      sv[j] = sv[j] * __expf(mv[j] - mn) + sum;
      mv[j] = mn;
    }
  }
#pragma unroll
  for (int j = 0; j < 4; j++) {
    redM[qx][kx * 4 + j] = mv[j];
    redS[qx][kx * 4 + j] = sv[j];
  }
  __syncthreads();
  if (tid < 64) {
    float mf = -1e30f;
#pragma unroll
    for (int i = 0; i < 16; i++) mf = fmaxf(mf, redM[i][tid]);
    float sf = 0.0f;
#pragma unroll
    for (int i = 0; i < 16; i++) sf += redS[i][tid] * __expf(redM[i][tid] - mf);
    Mp[((long long)(qs * nb + bl)) * NL75_TN + k0 + tid] = mf;
    Sp[((long long)(qs * nb + bl)) * NL75_TN + k0 + tid] = sf;
  }
}

// ------------- combine partial stats: M = max, S = sum S*exp(dM) ------------
// grid (nb), block 256. In-place safe when Mp==mW, Sp==izW, qsplit==1.
__global__ void nl75_sred(const float* Mp, const float* Sp, float* mW,
                          float* izW, int nb, int qsplit) {
  const int bl = blockIdx.x;
  for (int k = threadIdx.x; k < NL75_TN; k += 256) {
    float M = -1e30f;
    for (int qs = 0; qs < qsplit; qs++)
      M = fmaxf(M, Mp[((long long)(qs * nb + bl)) * NL75_TN + k]);
    float S = 0.0f;
    for (int qs = 0; qs < qsplit; qs++) {
      long long idx = ((long long)(qs * nb + bl)) * NL75_TN + k;
      S += Sp[idx] * __expf(Mp[idx] - M);
    }
    mW[(long long)bl * NL75_TN + k] = M;
    izW[(long long)bl * NL75_TN + k] = 1.0f / S;
  }
}

// ------------- attention apply + PV over a k-range: yPart[ks][m][q] ---------
// grid (32, ksplit, nb), block 256.
__global__ void nl75_attn(const float* projB, const float* mIn,
                          const float* izIn, float* yPart, int nb,
                          int ksplit) {
  __shared__ float thS[NL75_MID][68];
  __shared__ float phwS[NL75_MID][68];  // phase1: phi [m][k]; phase2: w [k][q]
  __shared__ float gS[NL75_MID][68];    // [k][m]
  __shared__ float mT[64], izT[64];
  const int qt = blockIdx.x, ks = blockIdx.y, bl = blockIdx.z;
  const int tid = threadIdx.x;
  const float* thB = projB + ((long long)(0 * nb + bl) * NL75_MID) * NL75_TN;
  const float* phB = projB + ((long long)(1 * nb + bl) * NL75_MID) * NL75_TN;
  const float* gB  = projB + ((long long)(2 * nb + bl) * NL75_MID) * NL75_TN;
  const int q0 = qt * 64;
  for (int i = tid; i < NL75_MID * 64; i += 256) {
    int m = i >> 6, qq = i & 63;
    thS[m][qq] = thB[(long long)m * NL75_TN + q0 + qq];
  }
  const int kx = tid & 15, qx = tid >> 4;
  float acc[4][4];  // y[m = kx*4+i][q = q0 + qx*4+j]
#pragma unroll
  for (int i = 0; i < 4; i++)
#pragma unroll
    for (int j = 0; j < 4; j++) acc[i][j] = 0.0f;
  const int ktN = 32 / ksplit;
  const int ktBeg = ks * ktN, ktEnd = ktBeg + ktN;
  for (int kt = ktBeg; kt < ktEnd; kt++) {
    __syncthreads();
    const int k0 = kt * 64;
    for (int i = tid; i < NL75_MID * 64; i += 256) {
      int m = i >> 6, k = i & 63;
      phwS[m][k] = phB[(long long)m * NL75_TN + k0 + k];
      gS[k][m]   = gB[(long long)m * NL75_TN + k0 + k];
    }
    if (tid < 64) {
      mT[tid]  = mIn[(long long)bl * NL75_TN + k0 + tid];
      izT[tid] = izIn[(long long)bl * NL75_TN + k0 + tid];
    }
    __syncthreads();
    float s[4][4];  // s[q-sub i][k-sub j]
#pragma unroll
    for (int i = 0; i < 4; i++)
#pragma unroll
      for (int j = 0; j < 4; j++) s[i][j] = 0.0f;
    for (int m = 0; m < NL75_MID; m++) {
      float av[4], bv[4];
#pragma unroll
      for (int i = 0; i < 4; i++) av[i] = thS[m][qx * 4 + i];
#pragma unroll
      for (int j = 0; j < 4; j++) bv[j] = phwS[m][kx * 4 + j];
#pragma unroll
      for (int i = 0; i < 4; i++)
#pragma unroll
        for (int j = 0; j < 4; j++) s[i][j] = fmaf(av[i], bv[j], s[i][j]);
    }
    __syncthreads();  // all reads of phi done before overwrite with w
#pragma unroll
    for (int j = 0; j < 4; j++) {
      int k = kx * 4 + j;
      float mk = mT[k], iz = izT[k];
#pragma unroll
      for (int i = 0; i < 4; i++)
        phwS[k][qx * 4 + i] = __expf(s[i][j] - mk) * iz;  // w[k][q-local]
    }
    __syncthreads();
    for (int k = 0; k < 64; k++) {
      float gv[4], wv[4];
#pragma unroll
      for (int i = 0; i < 4; i++) gv[i] = gS[k][kx * 4 + i];
#pragma unroll
      for (int j = 0; j < 4; j++) wv[j] = phwS[k][qx * 4 + j];
#pragma unroll
      for (int i = 0; i < 4; i++)
#pragma unroll
        for (int j = 0; j < 4; j++) acc[i][j] = fmaf(gv[i], wv[j], acc[i][j]);
    }
  }
  float* yB = yPart + ((long long)(ks * nb + bl) * NL75_MID) * NL75_TN;
#pragma unroll
  for (int i = 0; i < 4; i++)
#pragma unroll
    for (int j = 0; j < 4; j++)
      yB[(long long)(kx * 4 + i) * NL75_TN + q0 + qx * 4 + j] = acc[i][j];
}

// ------- fused refine GEMM + scatter + residual (sums ksplit y-partials) ----
// grid (16, 4, nb) = (cg: c-block of 8, t, bl), block 256.
__global__ void nl75_refsc(const float* yPart, const float* rW,
                           const float* rB, const float* pc, float* outP,
                           int bOff, int nb, int ksplit) {
  __shared__ float rwS[32][66];        // [oh][m]
  __shared__ float yS[NL75_MID][132];  // [m][qi], qi = i16*8 + cl (cl<8)
  const int cg = blockIdx.x, t = blockIdx.y, bl = blockIdx.z;
  const int b = bOff + bl, c0 = cg * 8, tid = threadIdx.x;
  for (int i = tid; i < 32 * NL75_MID; i += 256) {
    int oh = i >> 6, m = i & 63;
    rwS[oh][m] = rW[(long long)(t * 32 + oh) * NL75_MID + m];
  }
  for (int i = tid; i < NL75_MID * 128; i += 256) {
    int m = i >> 7, qi = i & 127;
    int i16 = qi >> 3, cl = qi & 7;
    long long off = (long long)m * NL75_TN + i16 * 128 + c0 + cl;
    float v = 0.0f;
    for (int ks = 0; ks < ksplit; ks++)
      v += yPart[((long long)(ks * nb + bl) * NL75_MID) * NL75_TN + off];
    yS[m][qi] = v;
  }
  __syncthreads();
  const int oh0 = (tid >> 5) * 4;  // 8 groups x 4 oh rows
  const int q4 = (tid & 31) * 4;   // 32 groups x 4 qi cols
  float acc[4][4];
#pragma unroll
  for (int i = 0; i < 4; i++) {
    float bias = rB[t * 32 + oh0 + i];
#pragma unroll
    for (int j = 0; j < 4; j++) acc[i][j] = bias;
  }
  for (int m = 0; m < NL75_MID; m++) {
    float yv[4];
#pragma unroll
    for (int j = 0; j < 4; j++) yv[j] = yS[m][q4 + j];
#pragma unroll
    for (int i = 0; i < 4; i++) {
      float w = rwS[oh0 + i][m];
#pragma unroll
      for (int j = 0; j < 4; j++) acc[i][j] = fmaf(w, yv[j], acc[i][j]);
    }
  }
#pragma unroll
  for (int i = 0; i < 4; i++) {
    int oh = oh0 + i;
#pragma unroll
    for (int j = 0; j < 4; j++) {
      int qi = q4 + j;
      int i16 = qi >> 3, cl = qi & 7;
      int n = oh * 16 + i16;
      long long idx = (((long long)b * 128 + c0 + cl) * 4 + t) * 512 + n;
      outP[idx] = fmaxf(acc[i][j], 0.0f) + pc[idx];
    }
  }
}

extern "C" void kernel_launch(void* const* d_in, const int* in_sizes, int n_in,
                              void* d_out, int out_size, void* d_ws, size_t ws_size,
                              hipStream_t stream) {
  const float* pc = (const float*)d_in[0];
  const float* tw = (const float*)d_in[1];
  const float* tb = (const float*)d_in[2];
  const float* pw = (const float*)d_in[3];
  const float* pb = (const float*)d_in[4];
  const float* gw = (const float*)d_in[5];
  const float* gb = (const float*)d_in[6];
  const float* rw = (const float*)d_in[7];
  const float* rb = (const float*)d_in[8];
  float* out = (float*)d_out;

  const size_t projPB = 3ull * NL75_MID * NL75_TN;  // fp32 per batch
  const size_t yPB = (size_t)NL75_MID * NL75_TN;    // fp32 per batch
  // full: nb=8, qsplit=4, ksplit=4
  const size_t needFull = (projPB * 8 + 2ull * 8 * NL75_TN +
                           2ull * 4 * 8 * NL75_TN + 4ull * 8 * yPB) * 4;
  // mid: nb=8, no split (aliased partials) — identical to r16 layout
  const size_t needMid = (projPB * 8 + 2ull * 8 * NL75_TN + 8ull * yPB) * 4;

  int nb, qsplit, ksplit;
  bool alias;
  if (ws_size >= needFull) { nb = 8; qsplit = 4; ksplit = 4; alias = false; }
  else if (ws_size >= needMid) { nb = 8; qsplit = 1; ksplit = 1; alias = true; }
  else { nb = 1; qsplit = 1; ksplit = 1; alias = true; }
  const int nloop = 8 / nb;

  float* projB = (float*)d_ws;
  float* mW = projB + projPB * nb;
  float* izW = mW + (size_t)nb * NL75_TN;
  float* Mp, * Sp, * yPart;
  if (alias) {
    Mp = mW; Sp = izW;
    yPart = izW + (size_t)nb * NL75_TN;
  } else {
    Mp = izW + (size_t)nb * NL75_TN;
    Sp = Mp + (size_t)qsplit * nb * NL75_TN;
    yPart = Sp + (size_t)qsplit * nb * NL75_TN;
  }

  for (int l = 0; l < nloop; l++) {
    const int bOff = l * nb;
    nl75_proj<<<dim3(32, 3, nb), 256, 0, stream>>>(pc, tw, tb, pw, pb, gw, gb,
                                                   projB, bOff, nb);
    nl75_stats<<<dim3(32 * qsplit, nb), 256, 0, stream>>>(projB, Mp, Sp, nb,
                                                          qsplit);
    nl75_sred<<<dim3(nb), 256, 0, stream>>>(Mp, Sp, mW, izW, nb, qsplit);
    nl75_attn<<<dim3(32, ksplit, nb), 256, 0, stream>>>(projB, mW, izW, yPart,
                                                        nb, ksplit);
    nl75_refsc<<<dim3(16, 4, nb), 256, 0, stream>>>(yPart, rw, rb, pc, out,
                                                    bOff, nb, ksplit);
  }
}

// Round 18
// 262.101 us; speedup vs baseline: 1.9790x; 1.4609x over previous
//
#include <hip/hip_runtime.h>

// NonLocalLayer  B=8, C=128, MID=64, OUT=128, T=4, N=512, TN=2048
// R18: bf16 MFMA for the GEMM phases (QK in stats+attn, PV in attn),
// fp32 accumulate. P round-trips LDS (fp32) per the verified m120 pattern.
// proj / sred / refsc unchanged from r17 (passed, absmax 7.8e-3).

constexpr int NL75_TN  = 2048;
constexpr int NL75_MID = 64;
constexpr int NL75_C   = 128;

typedef __attribute__((ext_vector_type(8))) short nl75_bf8;
typedef __attribute__((ext_vector_type(4))) float nl75_f4;

__device__ __forceinline__ unsigned short nl75_f2b(float f) {
  unsigned x = __float_as_uint(f);
  return (unsigned short)((x + 0x7fffu + ((x >> 16) & 1u)) >> 16);
}

__global__ void NonLocalLayer_75771813036638_kernel() {}

// ---------------- projections: proj[pj][bl][m][q] (unchanged) ---------------
__global__ void nl75_proj(const float* pc, const float* w0, const float* b0,
                          const float* w1, const float* b1, const float* w2,
                          const float* b2, float* projB, int bOff, int nb) {
  __shared__ float wT[NL75_C][68];
  const int qt = blockIdx.x, pj = blockIdx.y, bl = blockIdx.z;
  const int b = bOff + bl;
  const float* wp = (pj == 0) ? w0 : (pj == 1) ? w1 : w2;
  const float* bp = (pj == 0) ? b0 : (pj == 1) ? b1 : b2;
  const int tid = threadIdx.x;
  for (int i = tid; i < NL75_MID * NL75_C; i += 256)
    wT[i & 127][i >> 7] = wp[i];
  __syncthreads();
  const int lq = tid & 63, mg = tid >> 6;
  const int q = qt * 64 + lq, m0 = mg * 16;
  const float* pcb = pc + (long long)b * NL75_C * NL75_TN + q;
  float acc[16];
#pragma unroll
  for (int i = 0; i < 16; i++) acc[i] = bp[m0 + i];
  for (int c = 0; c < NL75_C; c++) {
    float p = pcb[(long long)c * NL75_TN];
#pragma unroll
    for (int i = 0; i < 16; i++) acc[i] = fmaf(wT[c][m0 + i], p, acc[i]);
  }
  float* op = projB + ((long long)(pj * nb + bl) * NL75_MID) * NL75_TN + q;
#pragma unroll
  for (int i = 0; i < 16; i++)
    op[(long long)(m0 + i) * NL75_TN] = fmaxf(acc[i], 0.0f);
}

// ---- helper: stage transposed bf16 tile dst[x][m] from src[m][x0+x] --------
// dst pitch 72 shorts. 256 threads, 64x64 tile. 16 loads + 4 b64 writes/thr.
__device__ __forceinline__ void nl75_stageT(unsigned short* dst,
                                            const float* src, int x0,
                                            int tid) {
  const int x = tid & 63;
  const int mb = (tid >> 6) * 4;
#pragma unroll
  for (int mi = 0; mi < 4; mi++) {
    const int m4 = mb + mi * 16;
    ushort4 v;
    v.x = nl75_f2b(src[(long long)(m4 + 0) * NL75_TN + x0 + x]);
    v.y = nl75_f2b(src[(long long)(m4 + 1) * NL75_TN + x0 + x]);
    v.z = nl75_f2b(src[(long long)(m4 + 2) * NL75_TN + x0 + x]);
    v.w = nl75_f2b(src[(long long)(m4 + 3) * NL75_TN + x0 + x]);
    *(ushort4*)&dst[x * 72 + m4] = v;
  }
}

// ------------- partial softmax stats over a q-range (MFMA QK) ---------------
// grid (32*qsplit, nb), block 256.
__global__ void nl75_stats(const float* projB, float* Mp, float* Sp, int nb,
                           int qsplit) {
  __shared__ unsigned short phT[64 * 72];  // [k][m] bf16
  __shared__ unsigned short thT[64 * 72];  // [q][m] bf16
  const int kt = blockIdx.x & 31, qs = blockIdx.x >> 5, bl = blockIdx.y;
  const int tid = threadIdx.x;
  const float* thB = projB + ((long long)(0 * nb + bl) * NL75_MID) * NL75_TN;
  const float* phB = projB + ((long long)(1 * nb + bl) * NL75_MID) * NL75_TN;
  const int k0 = kt * 64;
  nl75_stageT(phT, phB, k0, tid);
  __syncthreads();
  const int lane = tid & 63, w = tid >> 6;
  const int l15 = lane & 15, quad = lane >> 4;
  // B-frags for this wave's 16 k columns (held in regs across all q)
  const nl75_bf8 b0 = *(const nl75_bf8*)&phT[(w * 16 + l15) * 72 + quad * 8];
  const nl75_bf8 b1 =
      *(const nl75_bf8*)&phT[(w * 16 + l15) * 72 + 32 + quad * 8];
  float M = -1e30f, S = 0.0f;
  const int qtN = 32 / qsplit;
  const int qtBeg = qs * qtN, qtEnd = qtBeg + qtN;
  for (int qt = qtBeg; qt < qtEnd; qt++) {
    __syncthreads();
    nl75_stageT(thT, thB, qt * 64, tid);
    __syncthreads();
#pragma unroll
    for (int q16 = 0; q16 < 4; q16++) {
      const nl75_bf8 a0 =
          *(const nl75_bf8*)&thT[(q16 * 16 + l15) * 72 + quad * 8];
      const nl75_bf8 a1 =
          *(const nl75_bf8*)&thT[(q16 * 16 + l15) * 72 + 32 + quad * 8];
      nl75_f4 c = {0.0f, 0.0f, 0.0f, 0.0f};
      c = __builtin_amdgcn_mfma_f32_16x16x32_bf16(a0, b0, c, 0, 0, 0);
      c = __builtin_amdgcn_mfma_f32_16x16x32_bf16(a1, b1, c, 0, 0, 0);
      float mx = fmaxf(fmaxf(c[0], c[1]), fmaxf(c[2], c[3]));
      float nM = fmaxf(M, mx);
      float sum = __expf(c[0] - nM) + __expf(c[1] - nM) + __expf(c[2] - nM) +
                  __expf(c[3] - nM);
      S = S * __expf(M - nM) + sum;
      M = nM;
    }
  }
  // combine the 4 quads (lanes k, k+16, k+32, k+48 share a column)
#pragma unroll
  for (int off = 16; off <= 32; off <<= 1) {
    float Mo = __shfl_xor(M, off);
    float So = __shfl_xor(S, off);
    float nM = fmaxf(M, Mo);
    S = S * __expf(M - nM) + So * __expf(Mo - nM);
    M = nM;
  }
  if (quad == 0) {
    const long long base = ((long long)(qs * nb + bl)) * NL75_TN + k0;
    Mp[base + w * 16 + l15] = M;
    Sp[base + w * 16 + l15] = S;
  }
}

// ------------- combine partial stats (unchanged) ----------------------------
__global__ void nl75_sred(const float* Mp, const float* Sp, float* mW,
                          float* izW, int nb, int qsplit) {
  const int bl = blockIdx.x;
  for (int k = threadIdx.x; k < NL75_TN; k += 256) {
    float M = -1e30f;
    for (int qs = 0; qs < qsplit; qs++)
      M = fmaxf(M, Mp[((long long)(qs * nb + bl)) * NL75_TN + k]);
    float S = 0.0f;
    for (int qs = 0; qs < qsplit; qs++) {
      long long idx = ((long long)(qs * nb + bl)) * NL75_TN + k;
      S += Sp[idx] * __expf(Mp[idx] - M);
    }
    mW[(long long)bl * NL75_TN + k] = M;
    izW[(long long)bl * NL75_TN + k] = 1.0f / S;
  }
}

// ------------- attention apply + PV over a k-range (MFMA QK + PV) -----------
// grid (32, ksplit, nb), block 256. LDS ~45.5 KB.
__global__ void nl75_attn(const float* projB, const float* mIn,
                          const float* izIn, float* yPart, int nb,
                          int ksplit) {
  __shared__ unsigned short thT[64 * 72];  // [q][m] bf16 (staged once)
  __shared__ unsigned short phT[64 * 72];  // [k][m] bf16 (per kt)
  __shared__ unsigned short gS[64 * 72];   // [m][k] bf16 (per kt, no transp.)
  __shared__ float Pls[64 * 68];           // P [q][k] fp32; reused for y [m][q]
  __shared__ float mT[64], izT[64];
  const int qt = blockIdx.x, ks = blockIdx.y, bl = blockIdx.z;
  const int tid = threadIdx.x;
  const float* thB = projB + ((long long)(0 * nb + bl) * NL75_MID) * NL75_TN;
  const float* phB = projB + ((long long)(1 * nb + bl) * NL75_MID) * NL75_TN;
  const float* gB  = projB + ((long long)(2 * nb + bl) * NL75_MID) * NL75_TN;
  const int q0 = qt * 64;
  nl75_stageT(thT, thB, q0, tid);
  __syncthreads();
  const int lane = tid & 63, w = tid >> 6;
  const int l15 = lane & 15, quad = lane >> 4;
  // theta A-frags for this wave's 16 q rows (reused every kt)
  const nl75_bf8 aq0 = *(const nl75_bf8*)&thT[(w * 16 + l15) * 72 + quad * 8];
  const nl75_bf8 aq1 =
      *(const nl75_bf8*)&thT[(w * 16 + l15) * 72 + 32 + quad * 8];
  nl75_f4 yacc[4];
#pragma unroll
  for (int i = 0; i < 4; i++) yacc[i] = (nl75_f4){0.0f, 0.0f, 0.0f, 0.0f};
  const int ktN = 32 / ksplit;
  const int ktBeg = ks * ktN, ktEnd = ktBeg + ktN;
  for (int kt = ktBeg; kt < ktEnd; kt++) {
    const int k0 = kt * 64;
    __syncthreads();  // prior PV reads of gS/Pls done
    nl75_stageT(phT, phB, k0, tid);
    // g: [m][k] natural layout, ushort2 packed writes (conflict-free)
    for (int idx = tid; idx < 64 * 32; idx += 256) {
      const int m = idx >> 5, k2 = (idx & 31) * 2;
      const float* gp = &gB[(long long)m * NL75_TN + k0 + k2];
      ushort2 v;
      v.x = nl75_f2b(gp[0]);
      v.y = nl75_f2b(gp[1]);
      *(ushort2*)&gS[m * 72 + k2] = v;
    }
    if (tid < 64) {
      mT[tid] = mIn[(long long)bl * NL75_TN + k0 + tid];
      izT[tid] = izIn[(long long)bl * NL75_TN + k0 + tid];
    }
    __syncthreads();
    // QK: wave's 16q x 64k strip, 4 k-tiles x 2 MFMA; epilogue -> Pls
#pragma unroll
    for (int ktile = 0; ktile < 4; ktile++) {
      const nl75_bf8 b0 =
          *(const nl75_bf8*)&phT[(ktile * 16 + l15) * 72 + quad * 8];
      const nl75_bf8 b1 =
          *(const nl75_bf8*)&phT[(ktile * 16 + l15) * 72 + 32 + quad * 8];
      nl75_f4 c = {0.0f, 0.0f, 0.0f, 0.0f};
      c = __builtin_amdgcn_mfma_f32_16x16x32_bf16(aq0, b0, c, 0, 0, 0);
      c = __builtin_amdgcn_mfma_f32_16x16x32_bf16(aq1, b1, c, 0, 0, 0);
      const int kl = ktile * 16 + l15;
      const float mk = mT[kl], iz = izT[kl];
#pragma unroll
      for (int r = 0; r < 4; r++)
        Pls[(w * 16 + quad * 4 + r) * 68 + kl] = __expf(c[r] - mk) * iz;
    }
    __syncthreads();
    // PV: A = P rows (fp32 -> bf16), B = gS [m][k] direct
    const float* pr = &Pls[(w * 16 + l15) * 68];
    nl75_bf8 ap0, ap1;
    {
      nl75_f4 f0 = *(const nl75_f4*)&pr[quad * 8];
      nl75_f4 f1 = *(const nl75_f4*)&pr[quad * 8 + 4];
      nl75_f4 f2 = *(const nl75_f4*)&pr[32 + quad * 8];
      nl75_f4 f3 = *(const nl75_f4*)&pr[32 + quad * 8 + 4];
#pragma unroll
      for (int i = 0; i < 4; i++) {
        ap0[i] = (short)nl75_f2b(f0[i]);
        ap0[i + 4] = (short)nl75_f2b(f1[i]);
        ap1[i] = (short)nl75_f2b(f2[i]);
        ap1[i + 4] = (short)nl75_f2b(f3[i]);
      }
    }
#pragma unroll
    for (int mtile = 0; mtile < 4; mtile++) {
      const nl75_bf8 bg0 =
          *(const nl75_bf8*)&gS[(mtile * 16 + l15) * 72 + quad * 8];
      const nl75_bf8 bg1 =
          *(const nl75_bf8*)&gS[(mtile * 16 + l15) * 72 + 32 + quad * 8];
      yacc[mtile] =
          __builtin_amdgcn_mfma_f32_16x16x32_bf16(ap0, bg0, yacc[mtile], 0, 0, 0);
      yacc[mtile] =
          __builtin_amdgcn_mfma_f32_16x16x32_bf16(ap1, bg1, yacc[mtile], 0, 0, 0);
    }
  }
  __syncthreads();
  // write y via LDS transpose (reuse Pls as y[m][q]) then coalesced global
#pragma unroll
  for (int mtile = 0; mtile < 4; mtile++)
#pragma unroll
    for (int r = 0; r < 4; r++)
      Pls[(mtile * 16 + l15) * 68 + (w * 16 + quad * 4 + r)] = yacc[mtile][r];
  __syncthreads();
  float* yB = yPart + ((long long)(ks * nb + bl) * NL75_MID) * NL75_TN;
  const int qw = tid & 63;
#pragma unroll
  for (int mi = 0; mi < 16; mi++) {
    const int m = (tid >> 6) + mi * 4;
    yB[(long long)m * NL75_TN + q0 + qw] = Pls[m * 68 + qw];
  }
}

// ------- fused refine GEMM + scatter + residual (unchanged) -----------------
__global__ void nl75_refsc(const float* yPart, const float* rW,
                           const float* rB, const float* pc, float* outP,
                           int bOff, int nb, int ksplit) {
  __shared__ float rwS[32][66];
  __shared__ float yS[NL75_MID][132];
  const int cg = blockIdx.x, t = blockIdx.y, bl = blockIdx.z;
  const int b = bOff + bl, c0 = cg * 8, tid = threadIdx.x;
  for (int i = tid; i < 32 * NL75_MID; i += 256) {
    int oh = i >> 6, m = i & 63;
    rwS[oh][m] = rW[(long long)(t * 32 + oh) * NL75_MID + m];
  }
  for (int i = tid; i < NL75_MID * 128; i += 256) {
    int m = i >> 7, qi = i & 127;
    int i16 = qi >> 3, cl = qi & 7;
    long long off = (long long)m * NL75_TN + i16 * 128 + c0 + cl;
    float v = 0.0f;
    for (int ks = 0; ks < ksplit; ks++)
      v += yPart[((long long)(ks * nb + bl) * NL75_MID) * NL75_TN + off];
    yS[m][qi] = v;
  }
  __syncthreads();
  const int oh0 = (tid >> 5) * 4;
  const int q4 = (tid & 31) * 4;
  float acc[4][4];
#pragma unroll
  for (int i = 0; i < 4; i++) {
    float bias = rB[t * 32 + oh0 + i];
#pragma unroll
    for (int j = 0; j < 4; j++) acc[i][j] = bias;
  }
  for (int m = 0; m < NL75_MID; m++) {
    float yv[4];
#pragma unroll
    for (int j = 0; j < 4; j++) yv[j] = yS[m][q4 + j];
#pragma unroll
    for (int i = 0; i < 4; i++) {
      float w = rwS[oh0 + i][m];
#pragma unroll
      for (int j = 0; j < 4; j++) acc[i][j] = fmaf(w, yv[j], acc[i][j]);
    }
  }
#pragma unroll
  for (int i = 0; i < 4; i++) {
    int oh = oh0 + i;
#pragma unroll
    for (int j = 0; j < 4; j++) {
      int qi = q4 + j;
      int i16 = qi >> 3, cl = qi & 7;
      int n = oh * 16 + i16;
      long long idx = (((long long)b * 128 + c0 + cl) * 4 + t) * 512 + n;
      outP[idx] = fmaxf(acc[i][j], 0.0f) + pc[idx];
    }
  }
}

extern "C" void kernel_launch(void* const* d_in, const int* in_sizes, int n_in,
                              void* d_out, int out_size, void* d_ws, size_t ws_size,
                              hipStream_t stream) {
  const float* pc = (const float*)d_in[0];
  const float* tw = (const float*)d_in[1];
  const float* tb = (const float*)d_in[2];
  const float* pw = (const float*)d_in[3];
  const float* pb = (const float*)d_in[4];
  const float* gw = (const float*)d_in[5];
  const float* gb = (const float*)d_in[6];
  const float* rw = (const float*)d_in[7];
  const float* rb = (const float*)d_in[8];
  float* out = (float*)d_out;

  const size_t projPB = 3ull * NL75_MID * NL75_TN;
  const size_t yPB = (size_t)NL75_MID * NL75_TN;
  const size_t needFull = (projPB * 8 + 2ull * 8 * NL75_TN +
                           2ull * 4 * 8 * NL75_TN + 4ull * 8 * yPB) * 4;
  const size_t needMid = (projPB * 8 + 2ull * 8 * NL75_TN + 8ull * yPB) * 4;

  int nb, qsplit, ksplit;
  bool alias;
  if (ws_size >= needFull) { nb = 8; qsplit = 4; ksplit = 4; alias = false; }
  else if (ws_size >= needMid) { nb = 8; qsplit = 1; ksplit = 1; alias = true; }
  else { nb = 1; qsplit = 1; ksplit = 1; alias = true; }
  const int nloop = 8 / nb;

  float* projB = (float*)d_ws;
  float* mW = projB + projPB * nb;
  float* izW = mW + (size_t)nb * NL75_TN;
  float* Mp, * Sp, * yPart;
  if (alias) {
    Mp = mW; Sp = izW;
    yPart = izW + (size_t)nb * NL75_TN;
  } else {
    Mp = izW + (size_t)nb * NL75_TN;
    Sp = Mp + (size_t)qsplit * nb * NL75_TN;
    yPart = Sp + (size_t)qsplit * nb * NL75_TN;
  }

  for (int l = 0; l < nloop; l++) {
    const int bOff = l * nb;
    nl75_proj<<<dim3(32, 3, nb), 256, 0, stream>>>(pc, tw, tb, pw, pb, gw, gb,
                                                   projB, bOff, nb);
    nl75_stats<<<dim3(32 * qsplit, nb), 256, 0, stream>>>(projB, Mp, Sp, nb,
                                                          qsplit);
    nl75_sred<<<dim3(nb), 256, 0, stream>>>(Mp, Sp, mW, izW, nb, qsplit);
    nl75_attn<<<dim3(32, ksplit, nb), 256, 0, stream>>>(projB, mW, izW, yPart,
                                                        nb, ksplit);
    nl75_refsc<<<dim3(16, 4, nb), 256, 0, stream>>>(yPart, rw, rb, pc, out,
                                                    bOff, nb, ksplit);
  }
}